// Round 9
// baseline (3499.497 us; speedup 1.0000x reference)
//
#include <hip/hip_runtime.h>

typedef __bf16 bf16;
typedef __bf16 bf16x8 __attribute__((ext_vector_type(8)));
typedef __bf16 bf16x4 __attribute__((ext_vector_type(4)));
typedef float  f32x4  __attribute__((ext_vector_type(4)));

#define T_DIM 256
#define B_DIM 1024
#define HID   256
#define G4    1024
#define KIMG  784
#define KPAD  800
#define CTXD  64
#define MROWS (T_DIM*B_DIM)

__device__ __forceinline__ void gll16(const void* g, void* l) {
  __builtin_amdgcn_global_load_lds((const __attribute__((address_space(1))) void*)g,
                                   (__attribute__((address_space(3))) void*)l, 16, 0, 0);
}
__device__ __forceinline__ float sigm(float x) { return 1.f / (1.f + __expf(-x)); }
__device__ __forceinline__ float tanh_(float x) {
  x = fminf(fmaxf(x, -15.f), 15.f);
  float e = __expf(2.f * x);
  return (e - 1.f) / (e + 1.f);
}
// raw workgroup barrier: LDS visibility only; global loads stay in flight
__device__ __forceinline__ void bar_lds() {
  asm volatile("s_waitcnt lgkmcnt(0)\n\ts_barrier" ::: "memory");
}

// ---------------- prep kernels ----------------
__global__ void k_wiT(const float* __restrict__ wi, bf16* __restrict__ wiT) {
  int n = blockIdx.x;
  for (int k = threadIdx.x; k < KPAD; k += 256) {
    float v = (k < KIMG) ? wi[(long)k * G4 + n] : 0.f;
    wiT[(long)n * KPAD + k] = (bf16)v;
  }
}
__global__ void k_whT(const float* __restrict__ wh, bf16* __restrict__ whT) {
  int n = blockIdx.x;
  int k = threadIdx.x;
  whT[n * HID + k] = (bf16)wh[k * G4 + n];
}
__global__ void k_W0T(const float* __restrict__ a0k, const float* __restrict__ cr0k,
                      bf16* __restrict__ w0t) {
  int n = blockIdx.x;
  int k = threadIdx.x;
  float v = (n < 32) ? a0k[k * 32 + n] : cr0k[k * 32 + (n - 32)];
  w0t[n * HID + k] = (bf16)v;
}
__global__ void k_dirgate(const float* __restrict__ wi, const float* __restrict__ emb_k,
                          const float* __restrict__ emb_b, const float* __restrict__ b_lstm,
                          float* __restrict__ dir_gate) {
  int d = blockIdx.x;
  for (int n = threadIdx.x; n < G4; n += 256) {
    float s = b_lstm[n];
#pragma unroll
    for (int j = 0; j < 5; ++j) s += (emb_k[d * 5 + j] + emb_b[j]) * wi[(KIMG + j) * G4 + n];
    dir_gate[d * G4 + n] = s;
  }
}
__global__ void k_ctxgate(const float* __restrict__ wi, const float* __restrict__ ctx,
                          float* __restrict__ ctx_gate) {
  int b = blockIdx.x;
  __shared__ float cs[CTXD];
  if (threadIdx.x < CTXD) cs[threadIdx.x] = ctx[b * CTXD + threadIdx.x];
  __syncthreads();
  for (int n = threadIdx.x; n < G4; n += 256) {
    float s = 0.f;
#pragma unroll 8
    for (int k = 0; k < CTXD; ++k) s += cs[k] * wi[(KIMG + 5 + k) * G4 + n];
    ctx_gate[(long)b * G4 + n] = s;
  }
}

// ---------------- conv ----------------
#define CONV_ROWS 8
__global__ void k_conv(const float* __restrict__ img, const float* __restrict__ ck,
                       const float* __restrict__ cb, bf16* __restrict__ out) {
  __shared__ float s_img[CONV_ROWS * 243];
  __shared__ float s_k[432];
  __shared__ float s_b[16];
  long r0 = (long)blockIdx.x * CONV_ROWS;
  const float* src = img + r0 * 243;
  for (int i = threadIdx.x; i < CONV_ROWS * 243; i += 256) s_img[i] = src[i];
  for (int i = threadIdx.x; i < 432; i += 256) s_k[i] = ck[i];
  if (threadIdx.x < 16) s_b[threadIdx.x] = cb[threadIdx.x];
  __syncthreads();
  for (int idx = threadIdx.x; idx < CONV_ROWS * KPAD; idx += 256) {
    int r = idx / KPAD, c = idx % KPAD;
    float v = 0.f;
    if (c < KIMG) {
      int pix = c >> 4, ch = c & 15;
      int oy = pix / 7, ox = pix % 7;
      const float* ib = s_img + r * 243 + (oy * 9 + ox) * 3;
      v = s_b[ch];
#pragma unroll
      for (int ky = 0; ky < 3; ++ky)
#pragma unroll
        for (int kx = 0; kx < 3; ++kx)
#pragma unroll
          for (int cc = 0; cc < 3; ++cc)
            v += ib[(ky * 9 + kx) * 3 + cc] * s_k[((ky * 3 + kx) * 3 + cc) * 16 + ch];
      v = fmaxf(v, 0.f);
    }
    out[r0 * KPAD + idx] = (bf16)v;
  }
}

// ---------------- big GEMM: xg = conv_out @ wi_img^T(+tables) ----------------
// Output layout: xg[(t*B + b)*1024 + unit*4 + gate]  (unit 0..255, gate 0..3)
__global__ __launch_bounds__(256, 2)
void k_gemm_xg(const bf16* __restrict__ A, const bf16* __restrict__ Bt,
               const float* __restrict__ dir_gate, const float* __restrict__ ctx_gate,
               const int* __restrict__ agent_dir, bf16* __restrict__ xg) {
  __shared__ __align__(16) bf16 As[128 * 32];
  __shared__ __align__(16) bf16 Bs[128 * 32];
  const int bid = blockIdx.x;
  const int xcd = bid & 7, local = bid >> 3;
  const long m0 = (long)(xcd * 256 + (local >> 3)) * 128;
  const int n0 = (local & 7) * 128;
  const int tid = threadIdx.x, wave = tid >> 6, lane = tid & 63;
  const int row16 = lane & 15, k8 = (lane >> 4) * 8, rowg = (lane >> 4) * 4;
  const int wr = (wave >> 1) * 64, wc = (wave & 1) * 64;

  const bf16* a_src0 = A + (m0 + tid / 4) * KPAD + (tid % 4) * 8;
  const bf16* a_src1 = A + (m0 + 64 + tid / 4) * KPAD + (tid % 4) * 8;
  const bf16* b_src0 = Bt + (long)(n0 + tid / 4) * KPAD + (tid % 4) * 8;
  const bf16* b_src1 = Bt + (long)(n0 + 64 + tid / 4) * KPAD + (tid % 4) * 8;
  bf16* asd0 = As + wave * 512;
  bf16* asd1 = As + 2048 + wave * 512;
  bf16* bsd0 = Bs + wave * 512;
  bf16* bsd1 = Bs + 2048 + wave * 512;

  f32x4 acc[4][4];
  const f32x4 zero = {0.f, 0.f, 0.f, 0.f};
#pragma unroll
  for (int i = 0; i < 4; ++i)
#pragma unroll
    for (int j = 0; j < 4; ++j) acc[i][j] = zero;

  for (int ks = 0; ks < 25; ++ks) {
    const int ko = ks * 32;
    gll16(a_src0 + ko, asd0);
    gll16(a_src1 + ko, asd1);
    gll16(b_src0 + ko, bsd0);
    gll16(b_src1 + ko, bsd1);
    __syncthreads();
    bf16x8 af[4], bfr[4];
#pragma unroll
    for (int i = 0; i < 4; ++i)
      af[i] = *(const bf16x8*)(As + (wr + 16 * i + row16) * 32 + k8);
#pragma unroll
    for (int j = 0; j < 4; ++j)
      bfr[j] = *(const bf16x8*)(Bs + (wc + 16 * j + row16) * 32 + k8);
#pragma unroll
    for (int i = 0; i < 4; ++i)
#pragma unroll
      for (int j = 0; j < 4; ++j)
        acc[i][j] = __builtin_amdgcn_mfma_f32_16x16x32_bf16(af[i], bfr[j], acc[i][j], 0, 0, 0);
    __syncthreads();
  }
#pragma unroll
  for (int i = 0; i < 4; ++i)
#pragma unroll
    for (int j = 0; j < 4; ++j)
#pragma unroll
      for (int r = 0; r < 4; ++r) {
        long row = m0 + wr + 16 * i + rowg + r;
        int colj = n0 + wc + 16 * j + row16;
        int dv = agent_dir[row];
        float base = dir_gate[dv * G4 + colj] + ctx_gate[(long)(row & 1023) * G4 + colj];
        int u = colj & 255, g = colj >> 8;
        xg[row * G4 + u * 4 + g] = (bf16)(acc[i][j][r] + base);
      }
}

// ---------------- LSTM scan ----------------
// 64 blocks x 512 threads (8 waves, 2/EU -> 256 VGPR budget).
// Gate i: LDS-resident (135KB). Gates f,g: register-resident, loads PINNED
// with opaque asm so the RA cannot rematerialize/sink them (R6-R8 failure).
// Gate o: streamed from L2, wrap-around distance-1 double buffer.
// Raw lgkm-only barriers; xg(t+1) loaded in epilogue.
#define WPITCH 264
__global__ __launch_bounds__(512)
__attribute__((amdgpu_waves_per_eu(2, 2)))
void k_lstm(const bf16* __restrict__ xg, const bf16* __restrict__ whT,
            const int* __restrict__ dones,
            const float* __restrict__ c0, const float* __restrict__ h0,
            bf16* __restrict__ ys, float* __restrict__ cfin, float* __restrict__ hfin) {
  __shared__ __align__(16) bf16 h_lds[16 * WPITCH];
  __shared__ __align__(16) bf16 wc_lds[256 * WPITCH];   // gate-i weights, resident
  const int tid = threadIdx.x;
  const int w = tid >> 6, lane = tid & 63;
  const int col = lane & 15;
  const int k8 = (lane >> 4) * 8;
  const int rowg = (lane >> 4) * 4;
  const int b0 = blockIdx.x * 16;
  const int ju = 32 * w + col;

  // fill resident gate-i weight cache (rows n=0..255 of whT)
  for (int i = tid; i < 256 * 32; i += 512) {
    int row = i >> 5, chunk = i & 31;
    *(bf16x8*)(wc_lds + row * WPITCH + chunk * 8) =
        *(const bf16x8*)(whT + row * HID + chunk * 8);
  }
  for (int i = tid; i < 16 * HID; i += 512) {
    int m = i >> 8, j = i & 255;
    h_lds[m * WPITCH + j] = (bf16)h0[(b0 + m) * HID + j];
  }
  // gates f,g resident in registers: 2 gates x 2q x 8ks x 4 regs = 128 VGPR.
  // Opaque pin after each load: the RA can no longer prove the value equals
  // memory, so it cannot sink the load back into the loop (R6-R8 bug).
  bf16x8 wf[2][8], wg[2][8];
#pragma unroll
  for (int q = 0; q < 2; ++q)
#pragma unroll
    for (int ks = 0; ks < 8; ++ks) {
      wf[q][ks] = *(const bf16x8*)(whT + (long)(256 + ju + 16 * q) * HID + ks * 32 + k8);
      wg[q][ks] = *(const bf16x8*)(whT + (long)(512 + ju + 16 * q) * HID + ks * 32 + k8);
      asm volatile("" : "+v"(wf[q][ks]));
      asm volatile("" : "+v"(wg[q][ks]));
    }

  float creg[2][4], c0reg[2][4];
  bf16 h0b[2][4];
#pragma unroll
  for (int q = 0; q < 2; ++q)
#pragma unroll
    for (int r = 0; r < 4; ++r) {
      int j = ju + 16 * q;
      float v = c0[(b0 + rowg + r) * HID + j];
      creg[q][r] = v; c0reg[q][r] = v;
      h0b[q][r] = (bf16)h0[(b0 + rowg + r) * HID + j];
    }
  // gate-o stream bases
  const bf16* wo[2];
#pragma unroll
  for (int q = 0; q < 2; ++q)
    wo[q] = whT + (long)(768 + ju + 16 * q) * HID + k8;

  // prologue: done(0), xg(0), gate-o ks=0 fragments
  int4 dnA = *(const int4*)(dones + b0 + rowg);
  bf16x4 xc[2][4];
  {
    const bf16* xb = xg + (long)(b0 + rowg) * G4 + ju * 4;
#pragma unroll
    for (int q = 0; q < 2; ++q)
#pragma unroll
      for (int r = 0; r < 4; ++r)
        xc[q][r] = *(const bf16x4*)(xb + (long)r * G4 + 64 * q);
  }
  bf16x8 bo_cur[2], bo_nxt[2];
#pragma unroll
  for (int q = 0; q < 2; ++q) bo_cur[q] = *(const bf16x8*)(wo[q]);
  __syncthreads();

#pragma unroll 1
  for (int t = 0; t < T_DIM; ++t) {
    const int tn = (t + 1 < T_DIM) ? t + 1 : (T_DIM - 1);
    f32x4 acc[4][2];
    const f32x4 zero = {0.f, 0.f, 0.f, 0.f};
#pragma unroll
    for (int g = 0; g < 4; ++g) { acc[g][0] = zero; acc[g][1] = zero; }

    int4 dnB;
#pragma unroll
    for (int ks = 0; ks < 8; ++ks) {
      // wrap-around distance-1 gate-o prefetch (ks=7 issues next step's ks=0)
      {
        const int kn = (ks + 1) & 7;
#pragma unroll
        for (int q = 0; q < 2; ++q)
          bo_nxt[q] = *(const bf16x8*)(wo[q] + kn * 32);
      }
      bf16x8 a = *(const bf16x8*)(h_lds + col * WPITCH + ks * 32 + k8);
#pragma unroll
      for (int q = 0; q < 2; ++q) {
        bf16x8 bi = *(const bf16x8*)(wc_lds + (ju + 16 * q) * WPITCH + ks * 32 + k8);
        acc[0][q] = __builtin_amdgcn_mfma_f32_16x16x32_bf16(a, bi, acc[0][q], 0, 0, 0);
      }
#pragma unroll
      for (int q = 0; q < 2; ++q)
        acc[1][q] = __builtin_amdgcn_mfma_f32_16x16x32_bf16(a, wf[q][ks], acc[1][q], 0, 0, 0);
#pragma unroll
      for (int q = 0; q < 2; ++q)
        acc[2][q] = __builtin_amdgcn_mfma_f32_16x16x32_bf16(a, wg[q][ks], acc[2][q], 0, 0, 0);
#pragma unroll
      for (int q = 0; q < 2; ++q) {
        acc[3][q] = __builtin_amdgcn_mfma_f32_16x16x32_bf16(a, bo_cur[q], acc[3][q], 0, 0, 0);
        bo_cur[q] = bo_nxt[q];
      }
      if (ks == 2)
        dnB = *(const int4*)(dones + (long)tn * B_DIM + b0 + rowg);
    }
    bar_lds();   // h_lds reads complete (LDS only; globals stay in flight)

    int dc[4] = {dnA.x, dnA.y, dnA.z, dnA.w};
    int dx[4] = {dnB.x, dnB.y, dnB.z, dnB.w};
#pragma unroll
    for (int q = 0; q < 2; ++q)
#pragma unroll
      for (int r = 0; r < 4; ++r) {
        float c_old = dc[r] ? c0reg[q][r] : creg[q][r];
        float gi = acc[0][q][r] + (float)xc[q][r][0];
        float gf = acc[1][q][r] + (float)xc[q][r][1];
        float gg = acc[2][q][r] + (float)xc[q][r][2];
        float go = acc[3][q][r] + (float)xc[q][r][3];
        float cn = sigm(gf) * c_old + sigm(gi) * tanh_(gg);
        float hn = sigm(go) * tanh_(cn);
        creg[q][r] = cn;
        int m = rowg + r, j = ju + 16 * q;
        bf16 hb = (bf16)hn;
        ys[((long)t * B_DIM + b0 + m) * HID + j] = hb;
        h_lds[m * WPITCH + j] = dx[r] ? h0b[q][r] : hb;
        if (t == T_DIM - 1) {
          cfin[(b0 + m) * HID + j] = cn;
          hfin[(b0 + m) * HID + j] = hn;
        }
      }
    // prefetch next step's xg (consumed next epilogue; slack = one GEMM phase)
    {
      const bf16* xb = xg + (long)(tn * B_DIM + b0 + rowg) * G4 + ju * 4;
#pragma unroll
      for (int q = 0; q < 2; ++q)
#pragma unroll
        for (int r = 0; r < 4; ++r)
          xc[q][r] = *(const bf16x4*)(xb + (long)r * G4 + 64 * q);
    }
    dnA = dnB;
    bar_lds();   // h writes visible for next step's GEMM
  }
}

// ---------------- heads ----------------
__global__ __launch_bounds__(256, 2)
void k_heads1(const bf16* __restrict__ ys, const bf16* __restrict__ w0t,
              const float* __restrict__ a0b, const float* __restrict__ cr0b,
              bf16* __restrict__ h1) {
  __shared__ __align__(16) bf16 As[128 * 32];
  __shared__ __align__(16) bf16 Ws[64 * 264];
  const int tid = threadIdx.x, wave = tid >> 6, lane = tid & 63;
  const int row16 = lane & 15, k8 = (lane >> 4) * 8, rowg = (lane >> 4) * 4;
  const long m0 = (long)blockIdx.x * 128;
  for (int i = tid; i < 64 * 256; i += 256) {
    int n = i >> 8, k = i & 255;
    Ws[n * 264 + k] = w0t[i];
  }
  const bf16* a_src0 = ys + (m0 + tid / 4) * HID + (tid % 4) * 8;
  const bf16* a_src1 = ys + (m0 + 64 + tid / 4) * HID + (tid % 4) * 8;
  bf16* asd0 = As + wave * 512;
  bf16* asd1 = As + 2048 + wave * 512;
  f32x4 acc[2][4];
  const f32x4 zero = {0.f, 0.f, 0.f, 0.f};
#pragma unroll
  for (int i = 0; i < 2; ++i)
#pragma unroll
    for (int j = 0; j < 4; ++j) acc[i][j] = zero;
  for (int ks = 0; ks < 8; ++ks) {
    gll16(a_src0 + ks * 32, asd0);
    gll16(a_src1 + ks * 32, asd1);
    __syncthreads();
    bf16x8 bw[4];
#pragma unroll
    for (int j = 0; j < 4; ++j)
      bw[j] = *(const bf16x8*)(Ws + (16 * j + row16) * 264 + ks * 32 + k8);
#pragma unroll
    for (int i = 0; i < 2; ++i) {
      bf16x8 a = *(const bf16x8*)(As + (32 * wave + 16 * i + row16) * 32 + k8);
#pragma unroll
      for (int j = 0; j < 4; ++j)
        acc[i][j] = __builtin_amdgcn_mfma_f32_16x16x32_bf16(a, bw[j], acc[i][j], 0, 0, 0);
    }
    __syncthreads();
  }
#pragma unroll
  for (int i = 0; i < 2; ++i)
#pragma unroll
    for (int j = 0; j < 4; ++j)
#pragma unroll
      for (int r = 0; r < 4; ++r) {
        long row = m0 + 32 * wave + 16 * i + rowg + r;
        int n = 16 * j + row16;
        float bias = (n < 32) ? a0b[n] : cr0b[n - 32];
        h1[row * 64 + n] = (bf16)fmaxf(acc[i][j][r] + bias, 0.f);
      }
}

__global__ void k_heads2(const bf16* __restrict__ h1, const float* __restrict__ a1k,
                         const float* __restrict__ a1b, const float* __restrict__ cr1k,
                         const float* __restrict__ cr1b, float* __restrict__ logits,
                         float* __restrict__ value) {
  __shared__ float w2[32 * 8];
  int tid = threadIdx.x;
  if (tid < 224) { int k = tid / 7, c = tid % 7; w2[k * 8 + c] = a1k[tid]; }
  else if (tid < 256) { int k = tid - 224; w2[k * 8 + 7] = cr1k[k]; }
  __syncthreads();
  long r = (long)blockIdx.x * 256 + tid;
  const bf16* hp = h1 + r * 64;
  float acc7[7];
#pragma unroll
  for (int c = 0; c < 7; ++c) acc7[c] = a1b[c];
  float accv = cr1b[0];
#pragma unroll 4
  for (int k = 0; k < 32; ++k) {
    float av = (float)hp[k];
    float cv = (float)hp[32 + k];
#pragma unroll
    for (int c = 0; c < 7; ++c) acc7[c] += av * w2[k * 8 + c];
    accv += cv * w2[k * 8 + 7];
  }
#pragma unroll
  for (int c = 0; c < 7; ++c) logits[r * 7 + c] = acc7[c];
  value[r] = accv;
}

// ---------------- launch ----------------
extern "C" void kernel_launch(void* const* d_in, const int* in_sizes, int n_in,
                              void* d_out, int out_size, void* d_ws, size_t ws_size,
                              hipStream_t stream) {
  const float* image = (const float*)d_in[0];
  const int* agent_dir = (const int*)d_in[1];
  const int* dones = (const int*)d_in[2];
  const float* context = (const float*)d_in[3];
  const float* c0 = (const float*)d_in[4];
  const float* h0 = (const float*)d_in[5];
  const float* conv_k = (const float*)d_in[6];
  const float* conv_b = (const float*)d_in[7];
  const float* emb_k = (const float*)d_in[8];
  const float* emb_b = (const float*)d_in[9];
  const float* wi = (const float*)d_in[10];
  const float* wh = (const float*)d_in[11];
  const float* b_lstm = (const float*)d_in[12];
  const float* a0_k = (const float*)d_in[13];
  const float* a0_b = (const float*)d_in[14];
  const float* a1_k = (const float*)d_in[15];
  const float* a1_b = (const float*)d_in[16];
  const float* cr0_k = (const float*)d_in[17];
  const float* cr0_b = (const float*)d_in[18];
  const float* cr1_k = (const float*)d_in[19];
  const float* cr1_b = (const float*)d_in[20];

  char* ws = (char*)d_ws;
  const size_t off_conv = 0;                              // conv_out region; ys/h1 reuse
  const size_t off_xg   = 419430400ULL;
  const size_t off_wiT  = off_xg  + 536870912ULL;
  const size_t off_whT  = off_wiT + 1638400ULL;
  const size_t off_W0T  = off_whT + 524288ULL;
  const size_t off_dirg = off_W0T + 32768ULL;
  const size_t off_ctxg = off_dirg + 16384ULL;
  const size_t total    = off_ctxg + 4194304ULL;
  if (ws_size < total) return;

  bf16* conv_out = (bf16*)(ws + off_conv);
  bf16* xg       = (bf16*)(ws + off_xg);
  bf16* wiT      = (bf16*)(ws + off_wiT);
  bf16* whT      = (bf16*)(ws + off_whT);
  bf16* W0T      = (bf16*)(ws + off_W0T);
  float* dir_gate = (float*)(ws + off_dirg);
  float* ctx_gate = (float*)(ws + off_ctxg);
  bf16* ys = (bf16*)(ws + 0);               // reuses conv_out region (dead after GEMM)
  bf16* h1 = (bf16*)(ws + 134217728ULL);

  float* out_cfin = (float*)d_out;
  float* out_hfin = out_cfin + 262144;
  float* out_logits = out_cfin + 524288;
  float* out_value = out_cfin + 524288 + 1835008;

  k_wiT<<<1024, 256, 0, stream>>>(wi, wiT);
  k_whT<<<1024, 256, 0, stream>>>(wh, whT);
  k_W0T<<<64, 256, 0, stream>>>(a0_k, cr0_k, W0T);
  k_dirgate<<<4, 256, 0, stream>>>(wi, emb_k, emb_b, b_lstm, dir_gate);
  k_ctxgate<<<1024, 256, 0, stream>>>(wi, context, ctx_gate);
  k_conv<<<MROWS / CONV_ROWS, 256, 0, stream>>>(image, conv_k, conv_b, conv_out);
  k_gemm_xg<<<16384, 256, 0, stream>>>(conv_out, wiT, dir_gate, ctx_gate, agent_dir, xg);
  k_lstm<<<64, 512, 0, stream>>>(xg, whT, dones, c0, h0, ys, out_cfin, out_hfin);
  k_heads1<<<2048, 256, 0, stream>>>(ys, W0T, a0_b, cr0_b, h1);
  k_heads2<<<1024, 256, 0, stream>>>(h1, a1_k, a1_b, cr1_k, cr1_b, out_logits, out_value);
}

// Round 10
// 2935.806 us; speedup vs baseline: 1.1920x; 1.1920x over previous
//
#include <hip/hip_runtime.h>
#include <hip/hip_fp8.h>

typedef __bf16 bf16;
typedef __bf16 bf16x8 __attribute__((ext_vector_type(8)));
typedef __bf16 bf16x4 __attribute__((ext_vector_type(4)));
typedef float  f32x4  __attribute__((ext_vector_type(4)));

#define T_DIM 256
#define B_DIM 1024
#define HID   256
#define G4    1024
#define KIMG  784
#define KPAD  800
#define CTXD  64
#define MROWS (T_DIM*B_DIM)

__device__ __forceinline__ void gll16(const void* g, void* l) {
  __builtin_amdgcn_global_load_lds((const __attribute__((address_space(1))) void*)g,
                                   (__attribute__((address_space(3))) void*)l, 16, 0, 0);
}
__device__ __forceinline__ float sigm(float x) { return 1.f / (1.f + __expf(-x)); }
__device__ __forceinline__ float tanh_(float x) {
  x = fminf(fmaxf(x, -15.f), 15.f);
  float e = __expf(2.f * x);
  return (e - 1.f) / (e + 1.f);
}
__device__ __forceinline__ void bar_lds() {
  asm volatile("s_waitcnt lgkmcnt(0)\n\ts_barrier" ::: "memory");
}
__device__ __forceinline__ unsigned char to_fp8(float f) {
  __hip_fp8_e4m3 v(f);
  return *reinterpret_cast<unsigned char*>(&v);
}

// ---------------- prep kernels ----------------
__global__ void k_wiT(const float* __restrict__ wi, bf16* __restrict__ wiT) {
  int n = blockIdx.x;
  for (int k = threadIdx.x; k < KPAD; k += 256) {
    float v = (k < KIMG) ? wi[(long)k * G4 + n] : 0.f;
    wiT[(long)n * KPAD + k] = (bf16)v;
  }
}
__global__ void k_whT(const float* __restrict__ wh, bf16* __restrict__ whT) {
  int n = blockIdx.x;
  int k = threadIdx.x;
  whT[n * HID + k] = (bf16)wh[k * G4 + n];
}
// fp8 (e4m3) copies of gate-f and gate-o weight blocks, [n][k] layout
__global__ void k_wh8(const float* __restrict__ wh, unsigned char* __restrict__ wh8) {
  int n = blockIdx.x;
  int k = threadIdx.x;
  wh8[n * HID + k]         = to_fp8(wh[k * G4 + 256 + n]);  // gate f
  wh8[65536 + n * HID + k] = to_fp8(wh[k * G4 + 768 + n]);  // gate o
}
__global__ void k_W0T(const float* __restrict__ a0k, const float* __restrict__ cr0k,
                      bf16* __restrict__ w0t) {
  int n = blockIdx.x;
  int k = threadIdx.x;
  float v = (n < 32) ? a0k[k * 32 + n] : cr0k[k * 32 + (n - 32)];
  w0t[n * HID + k] = (bf16)v;
}
__global__ void k_dirgate(const float* __restrict__ wi, const float* __restrict__ emb_k,
                          const float* __restrict__ emb_b, const float* __restrict__ b_lstm,
                          float* __restrict__ dir_gate) {
  int d = blockIdx.x;
  for (int n = threadIdx.x; n < G4; n += 256) {
    float s = b_lstm[n];
#pragma unroll
    for (int j = 0; j < 5; ++j) s += (emb_k[d * 5 + j] + emb_b[j]) * wi[(KIMG + j) * G4 + n];
    dir_gate[d * G4 + n] = s;
  }
}
__global__ void k_ctxgate(const float* __restrict__ wi, const float* __restrict__ ctx,
                          float* __restrict__ ctx_gate) {
  int b = blockIdx.x;
  __shared__ float cs[CTXD];
  if (threadIdx.x < CTXD) cs[threadIdx.x] = ctx[b * CTXD + threadIdx.x];
  __syncthreads();
  for (int n = threadIdx.x; n < G4; n += 256) {
    float s = 0.f;
#pragma unroll 8
    for (int k = 0; k < CTXD; ++k) s += cs[k] * wi[(KIMG + 5 + k) * G4 + n];
    ctx_gate[(long)b * G4 + n] = s;
  }
}

// ---------------- conv ----------------
#define CONV_ROWS 8
__global__ void k_conv(const float* __restrict__ img, const float* __restrict__ ck,
                       const float* __restrict__ cb, bf16* __restrict__ out) {
  __shared__ float s_img[CONV_ROWS * 243];
  __shared__ float s_k[432];
  __shared__ float s_b[16];
  long r0 = (long)blockIdx.x * CONV_ROWS;
  const float* src = img + r0 * 243;
  for (int i = threadIdx.x; i < CONV_ROWS * 243; i += 256) s_img[i] = src[i];
  for (int i = threadIdx.x; i < 432; i += 256) s_k[i] = ck[i];
  if (threadIdx.x < 16) s_b[threadIdx.x] = cb[threadIdx.x];
  __syncthreads();
  for (int idx = threadIdx.x; idx < CONV_ROWS * KPAD; idx += 256) {
    int r = idx / KPAD, c = idx % KPAD;
    float v = 0.f;
    if (c < KIMG) {
      int pix = c >> 4, ch = c & 15;
      int oy = pix / 7, ox = pix % 7;
      const float* ib = s_img + r * 243 + (oy * 9 + ox) * 3;
      v = s_b[ch];
#pragma unroll
      for (int ky = 0; ky < 3; ++ky)
#pragma unroll
        for (int kx = 0; kx < 3; ++kx)
#pragma unroll
          for (int cc = 0; cc < 3; ++cc)
            v += ib[(ky * 9 + kx) * 3 + cc] * s_k[((ky * 3 + kx) * 3 + cc) * 16 + ch];
      v = fmaxf(v, 0.f);
    }
    out[r0 * KPAD + idx] = (bf16)v;
  }
}

// ---------------- big GEMM: xg = conv_out @ wi_img^T(+tables) ----------------
// Output layout: xg[(t*B + b)*1024 + unit*4 + gate]  (unit 0..255, gate 0..3)
__global__ __launch_bounds__(256, 2)
void k_gemm_xg(const bf16* __restrict__ A, const bf16* __restrict__ Bt,
               const float* __restrict__ dir_gate, const float* __restrict__ ctx_gate,
               const int* __restrict__ agent_dir, bf16* __restrict__ xg) {
  __shared__ __align__(16) bf16 As[128 * 32];
  __shared__ __align__(16) bf16 Bs[128 * 32];
  const int bid = blockIdx.x;
  const int xcd = bid & 7, local = bid >> 3;
  const long m0 = (long)(xcd * 256 + (local >> 3)) * 128;
  const int n0 = (local & 7) * 128;
  const int tid = threadIdx.x, wave = tid >> 6, lane = tid & 63;
  const int row16 = lane & 15, k8 = (lane >> 4) * 8, rowg = (lane >> 4) * 4;
  const int wr = (wave >> 1) * 64, wc = (wave & 1) * 64;

  const bf16* a_src0 = A + (m0 + tid / 4) * KPAD + (tid % 4) * 8;
  const bf16* a_src1 = A + (m0 + 64 + tid / 4) * KPAD + (tid % 4) * 8;
  const bf16* b_src0 = Bt + (long)(n0 + tid / 4) * KPAD + (tid % 4) * 8;
  const bf16* b_src1 = Bt + (long)(n0 + 64 + tid / 4) * KPAD + (tid % 4) * 8;
  bf16* asd0 = As + wave * 512;
  bf16* asd1 = As + 2048 + wave * 512;
  bf16* bsd0 = Bs + wave * 512;
  bf16* bsd1 = Bs + 2048 + wave * 512;

  f32x4 acc[4][4];
  const f32x4 zero = {0.f, 0.f, 0.f, 0.f};
#pragma unroll
  for (int i = 0; i < 4; ++i)
#pragma unroll
    for (int j = 0; j < 4; ++j) acc[i][j] = zero;

  for (int ks = 0; ks < 25; ++ks) {
    const int ko = ks * 32;
    gll16(a_src0 + ko, asd0);
    gll16(a_src1 + ko, asd1);
    gll16(b_src0 + ko, bsd0);
    gll16(b_src1 + ko, bsd1);
    __syncthreads();
    bf16x8 af[4], bfr[4];
#pragma unroll
    for (int i = 0; i < 4; ++i)
      af[i] = *(const bf16x8*)(As + (wr + 16 * i + row16) * 32 + k8);
#pragma unroll
    for (int j = 0; j < 4; ++j)
      bfr[j] = *(const bf16x8*)(Bs + (wc + 16 * j + row16) * 32 + k8);
#pragma unroll
    for (int i = 0; i < 4; ++i)
#pragma unroll
      for (int j = 0; j < 4; ++j)
        acc[i][j] = __builtin_amdgcn_mfma_f32_16x16x32_bf16(af[i], bfr[j], acc[i][j], 0, 0, 0);
    __syncthreads();
  }
#pragma unroll
  for (int i = 0; i < 4; ++i)
#pragma unroll
    for (int j = 0; j < 4; ++j)
#pragma unroll
      for (int r = 0; r < 4; ++r) {
        long row = m0 + wr + 16 * i + rowg + r;
        int colj = n0 + wc + 16 * j + row16;
        int dv = agent_dir[row];
        float base = dir_gate[dv * G4 + colj] + ctx_gate[(long)(row & 1023) * G4 + colj];
        int u = colj & 255, g = colj >> 8;
        xg[row * G4 + u * 4 + g] = (bf16)(acc[i][j][r] + base);
      }
}

// ---------------- LSTM scan ----------------
// 64 blocks x 512 threads. Per-CU weight-byte budget is the wall (measured
// R3/R4/R8: time tracks streamed KB). Residency plan:
//   gate i: bf16, LDS-resident (135 KB)
//   gate g: bf16, streamed (tanh path — keep precision)
//   gates f,o: fp8 e4m3, streamed (sigmoid slope <=0.25 damps quant noise)
// h kept in LDS in BOTH bf16 (for i,g MFMAs) and fp8 (for f,o MFMAs).
// Streamed: 256 KB/step (vs 384 in R8). Raw lgkm-only barriers.
#define WPITCH 264
__global__ __launch_bounds__(512)
void k_lstm(const bf16* __restrict__ xg, const bf16* __restrict__ whT,
            const unsigned char* __restrict__ wh8,
            const int* __restrict__ dones,
            const float* __restrict__ c0, const float* __restrict__ h0,
            bf16* __restrict__ ys, float* __restrict__ cfin, float* __restrict__ hfin) {
  __shared__ __align__(16) bf16 h_lds[16 * WPITCH];
  __shared__ __align__(16) unsigned char h8_lds[16 * WPITCH];
  __shared__ __align__(16) bf16 wc_lds[256 * WPITCH];   // gate-i weights, resident
  const int tid = threadIdx.x;
  const int w = tid >> 6, lane = tid & 63;
  const int col = lane & 15;
  const int kq = lane >> 4;
  const int k8 = kq * 8;
  const int rowg = kq * 4;
  const int b0 = blockIdx.x * 16;
  const int ju = 32 * w + col;

  for (int i = tid; i < 256 * 32; i += 512) {
    int row = i >> 5, chunk = i & 31;
    *(bf16x8*)(wc_lds + row * WPITCH + chunk * 8) =
        *(const bf16x8*)(whT + row * HID + chunk * 8);
  }
  for (int i = tid; i < 16 * HID; i += 512) {
    int m = i >> 8, j = i & 255;
    float v = h0[(b0 + m) * HID + j];
    h_lds[m * WPITCH + j] = (bf16)v;
    h8_lds[m * WPITCH + j] = to_fp8(v);
  }

  float creg[2][4], c0reg[2][4];
  bf16 h0b[2][4];
  unsigned char h0b8[2][4];
#pragma unroll
  for (int q = 0; q < 2; ++q)
#pragma unroll
    for (int r = 0; r < 4; ++r) {
      int j = ju + 16 * q;
      float v = c0[(b0 + rowg + r) * HID + j];
      creg[q][r] = v; c0reg[q][r] = v;
      float hv = h0[(b0 + rowg + r) * HID + j];
      h0b[q][r] = (bf16)hv;
      h0b8[q][r] = to_fp8(hv);
    }
  // stream bases: g (bf16), f/o (fp8)
  const bf16* wgp[2];
  const unsigned char* wfp[2];
  const unsigned char* wop[2];
#pragma unroll
  for (int q = 0; q < 2; ++q) {
    wgp[q] = whT + (long)(512 + ju + 16 * q) * HID + k8;
    wfp[q] = wh8 + (ju + 16 * q) * HID + k8;
    wop[q] = wh8 + 65536 + (ju + 16 * q) * HID + k8;
  }

  // prologue: done(0), xg(0), ks=0 stream fragments
  int4 dnA = *(const int4*)(dones + b0 + rowg);
  bf16x4 xc[2][4];
  {
    const bf16* xb = xg + (long)(b0 + rowg) * G4 + ju * 4;
#pragma unroll
    for (int q = 0; q < 2; ++q)
#pragma unroll
      for (int r = 0; r < 4; ++r)
        xc[q][r] = *(const bf16x4*)(xb + (long)r * G4 + 64 * q);
  }
  bf16x8 bg_cur[2], bg_nxt[2];
  long long bf_cur[2], bf_nxt[2], bo_cur[2], bo_nxt[2];
#pragma unroll
  for (int q = 0; q < 2; ++q) {
    bg_cur[q] = *(const bf16x8*)(wgp[q]);
    bf_cur[q] = *(const long long*)(wfp[q]);
    bo_cur[q] = *(const long long*)(wop[q]);
  }
  __syncthreads();

#pragma unroll 1
  for (int t = 0; t < T_DIM; ++t) {
    const int tn = (t + 1 < T_DIM) ? t + 1 : (T_DIM - 1);
    f32x4 acc[4][2];
    const f32x4 zero = {0.f, 0.f, 0.f, 0.f};
#pragma unroll
    for (int g = 0; g < 4; ++g) { acc[g][0] = zero; acc[g][1] = zero; }

    int4 dnB;
#pragma unroll
    for (int ks = 0; ks < 8; ++ks) {
      // wrap-around distance-1 prefetch (ks=7 issues next step's ks=0)
      {
        const int kn = (ks + 1) & 7;
#pragma unroll
        for (int q = 0; q < 2; ++q) {
          bg_nxt[q] = *(const bf16x8*)(wgp[q] + kn * 32);
          bf_nxt[q] = *(const long long*)(wfp[q] + kn * 32);
          bo_nxt[q] = *(const long long*)(wop[q] + kn * 32);
        }
      }
      bf16x8 a = *(const bf16x8*)(h_lds + col * WPITCH + ks * 32 + k8);
      long long a8 = *(const long long*)(h8_lds + col * WPITCH + ks * 32 + k8);
#pragma unroll
      for (int q = 0; q < 2; ++q) {
        bf16x8 bi = *(const bf16x8*)(wc_lds + (ju + 16 * q) * WPITCH + ks * 32 + k8);
        acc[0][q] = __builtin_amdgcn_mfma_f32_16x16x32_bf16(a, bi, acc[0][q], 0, 0, 0);
      }
#pragma unroll
      for (int q = 0; q < 2; ++q) {
        acc[1][q] = __builtin_amdgcn_mfma_f32_16x16x32_fp8_fp8(a8, bf_cur[q], acc[1][q], 0, 0, 0);
        acc[2][q] = __builtin_amdgcn_mfma_f32_16x16x32_bf16(a, bg_cur[q], acc[2][q], 0, 0, 0);
        acc[3][q] = __builtin_amdgcn_mfma_f32_16x16x32_fp8_fp8(a8, bo_cur[q], acc[3][q], 0, 0, 0);
        bg_cur[q] = bg_nxt[q]; bf_cur[q] = bf_nxt[q]; bo_cur[q] = bo_nxt[q];
      }
      if (ks == 2)
        dnB = *(const int4*)(dones + (long)tn * B_DIM + b0 + rowg);
    }
    bar_lds();   // h_lds/h8_lds reads complete; globals stay in flight

    int dc[4] = {dnA.x, dnA.y, dnA.z, dnA.w};
    int dx[4] = {dnB.x, dnB.y, dnB.z, dnB.w};
#pragma unroll
    for (int q = 0; q < 2; ++q)
#pragma unroll
      for (int r = 0; r < 4; ++r) {
        float c_old = dc[r] ? c0reg[q][r] : creg[q][r];
        float gi = acc[0][q][r] + (float)xc[q][r][0];
        float gf = acc[1][q][r] + (float)xc[q][r][1];
        float gg = acc[2][q][r] + (float)xc[q][r][2];
        float go = acc[3][q][r] + (float)xc[q][r][3];
        float cn = sigm(gf) * c_old + sigm(gi) * tanh_(gg);
        float hn = sigm(go) * tanh_(cn);
        creg[q][r] = cn;
        int m = rowg + r, j = ju + 16 * q;
        bf16 hb = (bf16)hn;
        ys[((long)t * B_DIM + b0 + m) * HID + j] = hb;
        h_lds[m * WPITCH + j] = dx[r] ? h0b[q][r] : hb;
        h8_lds[m * WPITCH + j] = dx[r] ? h0b8[q][r] : to_fp8(hn);
        if (t == T_DIM - 1) {
          cfin[(b0 + m) * HID + j] = cn;
          hfin[(b0 + m) * HID + j] = hn;
        }
      }
    // prefetch next step's xg (consumed next epilogue)
    {
      const bf16* xb = xg + (long)(tn * B_DIM + b0 + rowg) * G4 + ju * 4;
#pragma unroll
      for (int q = 0; q < 2; ++q)
#pragma unroll
        for (int r = 0; r < 4; ++r)
          xc[q][r] = *(const bf16x4*)(xb + (long)r * G4 + 64 * q);
    }
    dnA = dnB;
    bar_lds();   // h writes visible for next step's GEMM
  }
}

// ---------------- fused heads: ys @ W0 -> relu -> @ W1 -> logits/value ----
#define H1PITCH 66
__global__ __launch_bounds__(256, 2)
void k_heads(const bf16* __restrict__ ys, const bf16* __restrict__ w0t,
             const float* __restrict__ a0b, const float* __restrict__ cr0b,
             const float* __restrict__ a1k, const float* __restrict__ a1b,
             const float* __restrict__ cr1k, const float* __restrict__ cr1b,
             float* __restrict__ logits, float* __restrict__ value) {
  __shared__ __align__(16) bf16 As[128 * 32];
  __shared__ __align__(16) bf16 Ws[64 * 264];
  __shared__ bf16 h1_lds[128 * H1PITCH];
  __shared__ float w2[32 * 8];
  const int tid = threadIdx.x, wave = tid >> 6, lane = tid & 63;
  const int row16 = lane & 15, k8 = (lane >> 4) * 8, rowg = (lane >> 4) * 4;
  const long m0 = (long)blockIdx.x * 128;
  for (int i = tid; i < 64 * 256; i += 256) {
    int n = i >> 8, k = i & 255;
    Ws[n * 264 + k] = w0t[i];
  }
  if (tid < 224) { int k = tid / 7, c = tid % 7; w2[k * 8 + c] = a1k[tid]; }
  else if (tid < 256) { int k = tid - 224; w2[k * 8 + 7] = cr1k[k]; }
  const bf16* a_src0 = ys + (m0 + tid / 4) * HID + (tid % 4) * 8;
  const bf16* a_src1 = ys + (m0 + 64 + tid / 4) * HID + (tid % 4) * 8;
  bf16* asd0 = As + wave * 512;
  bf16* asd1 = As + 2048 + wave * 512;
  f32x4 acc[2][4];
  const f32x4 zero = {0.f, 0.f, 0.f, 0.f};
#pragma unroll
  for (int i = 0; i < 2; ++i)
#pragma unroll
    for (int j = 0; j < 4; ++j) acc[i][j] = zero;
  for (int ks = 0; ks < 8; ++ks) {
    gll16(a_src0 + ks * 32, asd0);
    gll16(a_src1 + ks * 32, asd1);
    __syncthreads();
    bf16x8 bw[4];
#pragma unroll
    for (int j = 0; j < 4; ++j)
      bw[j] = *(const bf16x8*)(Ws + (16 * j + row16) * 264 + ks * 32 + k8);
#pragma unroll
    for (int i = 0; i < 2; ++i) {
      bf16x8 a = *(const bf16x8*)(As + (32 * wave + 16 * i + row16) * 32 + k8);
#pragma unroll
      for (int j = 0; j < 4; ++j)
        acc[i][j] = __builtin_amdgcn_mfma_f32_16x16x32_bf16(a, bw[j], acc[i][j], 0, 0, 0);
    }
    __syncthreads();
  }
#pragma unroll
  for (int i = 0; i < 2; ++i)
#pragma unroll
    for (int j = 0; j < 4; ++j)
#pragma unroll
      for (int r = 0; r < 4; ++r) {
        int rl = 32 * wave + 16 * i + rowg + r;
        int n = 16 * j + row16;
        float bias = (n < 32) ? a0b[n] : cr0b[n - 32];
        h1_lds[rl * H1PITCH + n] = (bf16)fmaxf(acc[i][j][r] + bias, 0.f);
      }
  __syncthreads();
  if (tid < 128) {
    const bf16* hp = h1_lds + tid * H1PITCH;
    float acc7[7];
#pragma unroll
    for (int c = 0; c < 7; ++c) acc7[c] = a1b[c];
    float accv = cr1b[0];
#pragma unroll 4
    for (int k = 0; k < 32; ++k) {
      float av = (float)hp[k];
      float cv = (float)hp[32 + k];
#pragma unroll
      for (int c = 0; c < 7; ++c) acc7[c] += av * w2[k * 8 + c];
      accv += cv * w2[k * 8 + 7];
    }
    long row = m0 + tid;
#pragma unroll
    for (int c = 0; c < 7; ++c) logits[row * 7 + c] = acc7[c];
    value[row] = accv;
  }
}

// ---------------- launch ----------------
extern "C" void kernel_launch(void* const* d_in, const int* in_sizes, int n_in,
                              void* d_out, int out_size, void* d_ws, size_t ws_size,
                              hipStream_t stream) {
  const float* image = (const float*)d_in[0];
  const int* agent_dir = (const int*)d_in[1];
  const int* dones = (const int*)d_in[2];
  const float* context = (const float*)d_in[3];
  const float* c0 = (const float*)d_in[4];
  const float* h0 = (const float*)d_in[5];
  const float* conv_k = (const float*)d_in[6];
  const float* conv_b = (const float*)d_in[7];
  const float* emb_k = (const float*)d_in[8];
  const float* emb_b = (const float*)d_in[9];
  const float* wi = (const float*)d_in[10];
  const float* wh = (const float*)d_in[11];
  const float* b_lstm = (const float*)d_in[12];
  const float* a0_k = (const float*)d_in[13];
  const float* a0_b = (const float*)d_in[14];
  const float* a1_k = (const float*)d_in[15];
  const float* a1_b = (const float*)d_in[16];
  const float* cr0_k = (const float*)d_in[17];
  const float* cr0_b = (const float*)d_in[18];
  const float* cr1_k = (const float*)d_in[19];
  const float* cr1_b = (const float*)d_in[20];

  char* ws = (char*)d_ws;
  const size_t off_conv = 0;                              // conv_out region; ys reuse
  const size_t off_xg   = 419430400ULL;
  const size_t off_wiT  = off_xg  + 536870912ULL;
  const size_t off_whT  = off_wiT + 1638400ULL;
  const size_t off_W0T  = off_whT + 524288ULL;
  const size_t off_dirg = off_W0T + 32768ULL;
  const size_t off_ctxg = off_dirg + 16384ULL;
  const size_t off_wh8  = off_ctxg + 4194304ULL;
  const size_t total    = off_wh8 + 131072ULL;
  if (ws_size < total) return;

  bf16* conv_out = (bf16*)(ws + off_conv);
  bf16* xg       = (bf16*)(ws + off_xg);
  bf16* wiT      = (bf16*)(ws + off_wiT);
  bf16* whT      = (bf16*)(ws + off_whT);
  bf16* W0T      = (bf16*)(ws + off_W0T);
  float* dir_gate = (float*)(ws + off_dirg);
  float* ctx_gate = (float*)(ws + off_ctxg);
  unsigned char* wh8 = (unsigned char*)(ws + off_wh8);
  bf16* ys = (bf16*)(ws + 0);               // reuses conv_out region (dead after GEMM)

  float* out_cfin = (float*)d_out;
  float* out_hfin = out_cfin + 262144;
  float* out_logits = out_cfin + 524288;
  float* out_value = out_cfin + 524288 + 1835008;

  k_wiT<<<1024, 256, 0, stream>>>(wi, wiT);
  k_whT<<<1024, 256, 0, stream>>>(wh, whT);
  k_wh8<<<256, 256, 0, stream>>>(wh, wh8);
  k_W0T<<<64, 256, 0, stream>>>(a0_k, cr0_k, W0T);
  k_dirgate<<<4, 256, 0, stream>>>(wi, emb_k, emb_b, b_lstm, dir_gate);
  k_ctxgate<<<1024, 256, 0, stream>>>(wi, context, ctx_gate);
  k_conv<<<MROWS / CONV_ROWS, 256, 0, stream>>>(image, conv_k, conv_b, conv_out);
  k_gemm_xg<<<16384, 256, 0, stream>>>(conv_out, wiT, dir_gate, ctx_gate, agent_dir, xg);
  k_lstm<<<64, 512, 0, stream>>>(xg, whT, wh8, dones, c0, h0, ys, out_cfin, out_hfin);
  k_heads<<<2048, 256, 0, stream>>>(ys, W0T, a0_b, cr0_b, a1_k, a1_b, cr1_k, cr1_b,
                                    out_logits, out_value);
}